// Round 6
// baseline (2358.194 us; speedup 1.0000x reference)
//
#include <hip/hip_runtime.h>
#include <cstdint>
#include <cstddef>

#define Bsz 2048
#define Tseq 60
#define Fin 89
#define Hd 1024
#define G4 4096
#define KX 96
#define NOUT 30

typedef _Float16 half8 __attribute__((ext_vector_type(8)));
typedef float f32x4 __attribute__((ext_vector_type(4)));

template <int N> struct IC { static constexpr int value = N; };

__device__ __forceinline__ void gload_lds16(const void* g, void* l) {
  __builtin_amdgcn_global_load_lds((const __attribute__((address_space(1))) void*)g,
                                   (__attribute__((address_space(3))) void*)l,
                                   16, 0, 0);
}

__device__ __forceinline__ float sigmoidf_fast(float x) {
  return 1.0f / (1.0f + __expf(-x));
}

// ---------------------------------------------------------------------------
// Prep kernels (run once per launch; ws is re-poisoned before every call)
// ---------------------------------------------------------------------------

// x [B][T][Fin] fp32 -> xp [T][B][KX] fp16, zero-padded k in [Fin, KX)
__global__ __launch_bounds__(256) void convert_x(const float* __restrict__ x,
                                                 _Float16* __restrict__ xp) {
  int idx = blockIdx.x * 256 + threadIdx.x;   // < Tseq*Bsz*KX
  int k = idx % KX;
  int b = (idx / KX) % Bsz;
  int t = idx / (KX * Bsz);
  float v = (k < Fin) ? x[((size_t)b * Tseq + t) * Fin + k] : 0.0f;
  xp[idx] = (_Float16)v;
}

// Pack W (ktbase=0, kvalid=89) and U (ktbase=3, kvalid=1024) into the
// MFMA-fragment-ordered B buffer:
//   Bswz[((jb*35 + kt)*4 + p)*512 + lane*8 + e]  (halfs)
//     = src[k][n],  n = p*1024 + jb*16 + (lane&15),
//                   k = (kt-ktbase)*32 + (lane>>4)*8 + e   (0 if k >= kvalid)
// A wave reading (kt,p) at lane*16B gets exactly its 16x16x32 B-fragment.
__global__ __launch_bounds__(256) void pack_B(const float* __restrict__ src,
                                              int kvalid, int ktbase,
                                              _Float16* __restrict__ Bswz) {
  __shared__ float tile[32][33];
  int n0 = blockIdx.x * 32;
  int k0 = blockIdx.y * 32;
  int tx = threadIdx.x, ty = threadIdx.y;
  for (int i = ty; i < 32; i += 8) {
    int k = k0 + i;
    tile[i][tx] = (k < kvalid) ? src[(size_t)k * G4 + n0 + tx] : 0.0f;
  }
  __syncthreads();
  int kt   = ktbase + (k0 >> 5);
  int quad = (tx >> 3) & 3;
  int e    = tx & 7;
  for (int i = ty; i < 32; i += 8) {
    int n = n0 + i;
    int p = n >> 10;
    int jj = n & 1023;
    int jb = jj >> 4;
    int l16 = jj & 15;
    int lane = quad * 16 + l16;
    size_t dst = ((size_t)(jb * 35 + kt) * 4 + p) * 512 + lane * 8 + e;
    Bswz[dst] = (_Float16)tile[tx][i];
  }
}

// ---------------------------------------------------------------------------
// One LSTM step (launched 60x; kernel boundary gives cross-XCD coherence).
// Tile: 128 batch rows x [4 gates x 16 hidden units]. Grid 64x16 = 1024
// blocks = 4 blocks/CU (launch_bounds(256,4)), 16 waves/CU. jb is the fast
// grid dim -> XCD round-robin pins each jb's Bswz slice in one XCD's L2.
//
// Wave w: rows m0+32w..+31 (2 MFMA row-tiles, disjoint across waves -> no
// redundant A reads), all 64 N-cols. Lane holds (i,f,g,o) of hidden unit
// j0+(lane&15) -> register-only gate epilogue, shuffle-free.
//
// A (x_t / h) staged in LDS via global_load_lds with the XOR chunk swizzle
// (conflict-free ds_read_b128, dense 64B staging lines). B comes STRAIGHT
// from global (Bswz) into registers: 4 dwordx4 per wave per K-subtile,
// double-buffered one subtile ahead (no barrier dependency; L1 dedups the
// 4 waves reading the same fragments). LDS traffic and barrier-drain bytes
// are halved vs staging both operands.
// ---------------------------------------------------------------------------
__global__ __launch_bounds__(256, 4) void lstm_step(
    const _Float16* __restrict__ xp_t,  // [Bsz][KX]  (this timestep)
    const _Float16* __restrict__ Bswz,  // packed W(kt 0..2) + U(kt 3..34)
    const float*    __restrict__ bias,  // [G4]
    const _Float16* __restrict__ h_in,  // [Bsz][Hd]
    _Float16*       __restrict__ h_out, // [Bsz][Hd]
    float*          __restrict__ cst,   // [Bsz][Hd]
    int skip_h)                          // t==0: skip h@U, c_prev = 0
{
  __shared__ __align__(16) _Float16 As[3 * 4096];  // up to 3 subtiles x 8 KB

  const int tid  = threadIdx.x;
  const int wave = tid >> 6;
  const int lane = tid & 63;
  const int quad = lane >> 4;
  const int l16  = lane & 15;
  const int jb = blockIdx.x;         // 0..63  -> hidden-unit base j0 = 16*jb
  const int m0 = blockIdx.y * 128;   // batch-row base
  const int j0 = jb * 16;

  const int srow = lane >> 2;                      // staging row in unit
  const int qg   = (lane & 3) ^ ((lane >> 3) & 3); // staging global chunk
  const int sA   = quad ^ ((l16 >> 1) & 3);        // fragment LDS slot
  const int j    = j0 + l16;
  const int aoff = l16 * 32 + sA * 8;              // frag offset in unit
  const int uA   = wave * 2;                       // wave's A units (2)

  const _Float16* Bb = Bswz + (size_t)jb * (35 * 2048) + lane * 8;

  float bv[4];
#pragma unroll
  for (int p = 0; p < 4; ++p) bv[p] = bias[p * Hd + j];

  f32x4 acc[2][4];
#pragma unroll
  for (int mi = 0; mi < 2; ++mi)
#pragma unroll
    for (int p = 0; p < 4; ++p)
      acc[mi][p] = f32x4{bv[p], bv[p], bv[p], bv[p]};

  const int ktmax = skip_h ? 2 : 34;

  half8 bq0[4], bq1[4];
#pragma unroll
  for (int p = 0; p < 4; ++p) bq0[p] = *(const half8*)(Bb + p * 512);

  auto stage = [&](auto ncI, const _Float16* __restrict__ Ab, int strA,
                   int k0g) {
    constexpr int NC = decltype(ncI)::value;
    __syncthreads();  // previous round's ds_reads done before overwrite
#pragma unroll
    for (int ii = 0; ii < NC * 2; ++ii) {
      int i = ii * 4 + wave;
      int st = i >> 3, ci = i & 7;
      gload_lds16(Ab + (size_t)(m0 + ci * 16 + srow) * strA + k0g + st * 32 + qg * 8,
                  &As[st * 4096 + ci * 512]);
    }
    __syncthreads();  // drains vmcnt(0): A tiles landed
  };

  // one K=32 subtile: prefetch next B fragments (opposite buffer), read A
  // fragments from LDS, 8 MFMAs. Parity P = which buffer holds CURRENT B.
  auto sub = [&](auto parI, int ktg, int stl) {
    constexpr int P = decltype(parI)::value;
    int ktn = (ktg < ktmax) ? ktg + 1 : ktg;
    const _Float16* bp = Bb + (size_t)ktn * 2048;
    if constexpr (P == 0) {
#pragma unroll
      for (int p = 0; p < 4; ++p) bq1[p] = *(const half8*)(bp + p * 512);
    } else {
#pragma unroll
      for (int p = 0; p < 4; ++p) bq0[p] = *(const half8*)(bp + p * 512);
    }
    half8 a0 = *(const half8*)&As[stl * 4096 + uA * 512 + aoff];
    half8 a1 = *(const half8*)&As[stl * 4096 + (uA + 1) * 512 + aoff];
    if constexpr (P == 0) {
#pragma unroll
      for (int p = 0; p < 4; ++p) {
        acc[0][p] = __builtin_amdgcn_mfma_f32_16x16x32_f16(a0, bq0[p],
                                                           acc[0][p], 0, 0, 0);
        acc[1][p] = __builtin_amdgcn_mfma_f32_16x16x32_f16(a1, bq0[p],
                                                           acc[1][p], 0, 0, 0);
      }
    } else {
#pragma unroll
      for (int p = 0; p < 4; ++p) {
        acc[0][p] = __builtin_amdgcn_mfma_f32_16x16x32_f16(a0, bq1[p],
                                                           acc[0][p], 0, 0, 0);
        acc[1][p] = __builtin_amdgcn_mfma_f32_16x16x32_f16(a1, bq1[p],
                                                           acc[1][p], 0, 0, 0);
      }
    }
  };

  // x_t @ W : kt 0..2 (K=96), one barrier pair
  stage(IC<3>{}, xp_t, KX, 0);
  sub(IC<0>{}, 0, 0);
  sub(IC<1>{}, 1, 1);
  sub(IC<0>{}, 2, 2);   // prefetches kt=3 into bq1

  // h_{t-1} @ U : 16 rounds of BK=64 (skipped at t=0, h_0 = 0)
  if (!skip_h) {
    for (int r = 0; r < 16; ++r) {
      stage(IC<2>{}, h_in, Hd, r * 64);
      sub(IC<1>{}, 3 + 2 * r, 0);   // uses bq1, prefetches bq0
      sub(IC<0>{}, 4 + 2 * r, 1);   // uses bq0, prefetches bq1
    }
  }

  // epilogue: lane holds i,f,g,o for hidden unit j, rows quad*4+r (m89 layout)
#pragma unroll
  for (int mi = 0; mi < 2; ++mi) {
#pragma unroll
    for (int r = 0; r < 4; ++r) {
      int row = m0 + wave * 32 + mi * 16 + quad * 4 + r;
      size_t idx = (size_t)row * Hd + j;
      float iv = sigmoidf_fast(acc[mi][0][r]);
      float fv = sigmoidf_fast(acc[mi][1][r]);
      float gv = fmaxf(acc[mi][2][r], 0.0f);   // relu candidate
      float ov = sigmoidf_fast(acc[mi][3][r]);
      float cprev = skip_h ? 0.0f : cst[idx];  // c_0 = 0 folded in
      float cv = fv * cprev + iv * gv;
      cst[idx] = cv;
      float hv = ov * fmaxf(cv, 0.0f);         // relu on cell output
      h_out[idx] = (_Float16)hv;
    }
  }
}

// ---------------------------------------------------------------------------
// y[b][o] = bd[o] + sum_k h[b][k] * Wd[k][o]
// ---------------------------------------------------------------------------
__global__ __launch_bounds__(256) void final_dense(const _Float16* __restrict__ h,
                                                   const float* __restrict__ Wd,
                                                   const float* __restrict__ bd,
                                                   float* __restrict__ y) {
  __shared__ float hs[Hd];
  __shared__ float red[8][32];
  int bi = blockIdx.x;
  for (int k = threadIdx.x; k < Hd; k += 256)
    hs[k] = (float)h[(size_t)bi * Hd + k];
  __syncthreads();
  int o  = threadIdx.x & 31;
  int ch = threadIdx.x >> 5;
  float p = 0.0f;
  if (o < NOUT) {
    int k0 = ch * (Hd / 8);
    for (int k = k0; k < k0 + (Hd / 8); ++k)
      p += hs[k] * Wd[(size_t)k * NOUT + o];
  }
  red[ch][o] = p;
  __syncthreads();
  if (threadIdx.x < NOUT) {
    float s = bd[threadIdx.x];
    for (int c2 = 0; c2 < 8; ++c2) s += red[c2][threadIdx.x];
    y[(size_t)bi * NOUT + threadIdx.x] = s;
  }
}

// ---------------------------------------------------------------------------

extern "C" void kernel_launch(void* const* d_in, const int* in_sizes, int n_in,
                              void* d_out, int out_size, void* d_ws, size_t ws_size,
                              hipStream_t stream) {
  const float* x  = (const float*)d_in[0];
  const float* W  = (const float*)d_in[1];
  const float* U  = (const float*)d_in[2];
  const float* b  = (const float*)d_in[3];
  const float* Wd = (const float*)d_in[4];
  const float* bd = (const float*)d_in[5];
  float* y = (float*)d_out;

  char* ws = (char*)d_ws;
  _Float16* xp   = (_Float16*)ws; ws += (size_t)Tseq * Bsz * KX * 2;   // 23.6 MB
  _Float16* Bswz = (_Float16*)ws; ws += (size_t)64 * 35 * 2048 * 2;    // 9.2 MB
  _Float16* hb0  = (_Float16*)ws; ws += (size_t)Bsz * Hd * 2;          // 4.2 MB
  _Float16* hb1  = (_Float16*)ws; ws += (size_t)Bsz * Hd * 2;          // 4.2 MB
  float*    cst  = (float*)ws;    ws += (size_t)Bsz * Hd * 4;          // 8.4 MB

  convert_x<<<(Tseq * Bsz * KX) / 256, 256, 0, stream>>>(x, xp);
  pack_B<<<dim3(G4 / 32, 3),       dim3(32, 8), 0, stream>>>(W, Fin, 0, Bswz);
  pack_B<<<dim3(G4 / 32, Hd / 32), dim3(32, 8), 0, stream>>>(U, Hd,  3, Bswz);

  for (int t = 0; t < Tseq; ++t) {
    const _Float16* hin  = ((t - 1) & 1) ? hb1 : hb0;   // unused at t=0
    _Float16*       hout = (t & 1) ? hb1 : hb0;
    lstm_step<<<dim3(64, 16), 256, 0, stream>>>(
        xp + (size_t)t * (Bsz * KX), Bswz, b,
        (t == 0) ? hb0 : hin, hout, cst, (t == 0) ? 1 : 0);
  }

  // h_{59} is in hb1 (59 & 1 == 1)
  final_dense<<<Bsz, 256, 0, stream>>>(hb1, Wd, bd, y);
}

// Round 7
// 1707.651 us; speedup vs baseline: 1.3810x; 1.3810x over previous
//
#include <hip/hip_runtime.h>
#include <cstdint>
#include <cstddef>

#define Bsz 2048
#define Tseq 60
#define Fin 89
#define Hd 1024
#define G4 4096
#define KX 96
#define NOUT 30

typedef _Float16 half8 __attribute__((ext_vector_type(8)));
typedef float f32x4 __attribute__((ext_vector_type(4)));

template <int N> struct IC { static constexpr int value = N; };

__device__ __forceinline__ void gload_lds16(const void* g, void* l) {
  __builtin_amdgcn_global_load_lds((const __attribute__((address_space(1))) void*)g,
                                   (__attribute__((address_space(3))) void*)l,
                                   16, 0, 0);
}

__device__ __forceinline__ float sigmoidf_fast(float x) {
  return 1.0f / (1.0f + __expf(-x));
}

// ---------------------------------------------------------------------------
// Prep kernels (run once per launch; ws is re-poisoned before every call)
// ---------------------------------------------------------------------------

// x [B][T][Fin] fp32 -> xp [T][B][KX] fp16, zero-padded k in [Fin, KX)
__global__ __launch_bounds__(256) void convert_x(const float* __restrict__ x,
                                                 _Float16* __restrict__ xp) {
  int idx = blockIdx.x * 256 + threadIdx.x;   // < Tseq*Bsz*KX
  int k = idx % KX;
  int b = (idx / KX) % Bsz;
  int t = idx / (KX * Bsz);
  float v = (k < Fin) ? x[((size_t)b * Tseq + t) * Fin + k] : 0.0f;
  xp[idx] = (_Float16)v;
}

// W [Fin][G4] fp32 -> Wpt [G4][KX] fp16 (B^T layout, zero rows k>=Fin)
__global__ __launch_bounds__(256) void transpose_W(const float* __restrict__ W,
                                                   _Float16* __restrict__ Wpt) {
  __shared__ float tile[32][33];
  int n0 = blockIdx.x * 32;
  int k0 = blockIdx.y * 32;
  int tx = threadIdx.x, ty = threadIdx.y;
  for (int i = ty; i < 32; i += 8) {
    int k = k0 + i;
    tile[i][tx] = (k < Fin) ? W[(size_t)k * G4 + n0 + tx] : 0.0f;
  }
  __syncthreads();
  for (int i = ty; i < 32; i += 8)
    Wpt[(size_t)(n0 + i) * KX + k0 + tx] = (_Float16)tile[tx][i];
}

// U [Hd][G4] fp32 -> Upt [G4][Hd] fp16 (B^T layout)
__global__ __launch_bounds__(256) void transpose_U(const float* __restrict__ U,
                                                   _Float16* __restrict__ Upt) {
  __shared__ float tile[32][33];
  int n0 = blockIdx.x * 32;
  int k0 = blockIdx.y * 32;
  int tx = threadIdx.x, ty = threadIdx.y;
  for (int i = ty; i < 32; i += 8)
    tile[i][tx] = U[(size_t)(k0 + i) * G4 + n0 + tx];
  __syncthreads();
  for (int i = ty; i < 32; i += 8)
    Upt[(size_t)(n0 + i) * Hd + k0 + tx] = (_Float16)tile[tx][i];
}

// ---------------------------------------------------------------------------
// One LSTM step (launched 60x; kernel boundary gives cross-XCD coherence).
// This is the R4 structure (measured best: 26 us/step) with ONE change:
// the grid is ordered j-fastest, so XCD = linear%8 = jb%8 is CONSTANT per
// hidden-unit slice -> each j-slice's U panel (0.26 MB) pins to exactly one
// XCD's L2 instead of being re-fetched into all 8 L2s every step. The
// (smaller) h operand becomes the replicated one: ~34 MB/step vs U's 67.
//
// Block tile: 128 batch rows x [4 gates x 32 hidden units]. Wave w: rows
// 64*(w>>1)..+63, hidden units j0+16*(w&1)..+15, all 4 gates -> each lane
// holds (i,f,g,o) of one hidden unit in registers; epilogue is shuffle-free.
//
// LDS: 16-row units of 32 halfs/row, 16B chunks XOR-swizzled (slot s of row
// r holds global chunk s^((r>>1)&3)) -> dense 64B staging lines AND
// conflict-free ds_read_b128 fragment reads (uniform 2/bank, free per m136).
//
// Rounds: x@W as one K=96 round, h@U as 16 rounds of BK=64 -> 17 barrier
// pairs/step, 32-48 MFMA per pair (R5's BK=128 and R6's global-B both
// regressed; this quantum is the measured optimum at 2 blocks/CU).
// ---------------------------------------------------------------------------
__global__ __launch_bounds__(256, 2) void lstm_step(
    const _Float16* __restrict__ xp_t,  // [Bsz][KX]  (this timestep)
    const _Float16* __restrict__ Wpt,   // [G4][KX]   (B^T)
    const _Float16* __restrict__ Upt,   // [G4][Hd]   (B^T)
    const float*    __restrict__ bias,  // [G4]
    const _Float16* __restrict__ h_in,  // [Bsz][Hd]
    _Float16*       __restrict__ h_out, // [Bsz][Hd]
    float*          __restrict__ cst,   // [Bsz][Hd]
    int skip_h)                          // t==0: skip h@U, c_prev = 0
{
  __shared__ __align__(16) _Float16 As[3 * 4096];  // 3 subtiles x 8 units
  __shared__ __align__(16) _Float16 Bs[3 * 4096];

  const int tid  = threadIdx.x;
  const int wave = tid >> 6;
  const int lane = tid & 63;
  const int quad = lane >> 4;
  const int l16  = lane & 15;
  const int j0 = blockIdx.x * 32;    // hidden-unit base (FAST dim -> XCD-pinned)
  const int m0 = blockIdx.y * 128;   // batch-row base

  const int srow = lane >> 2;                      // staging row in unit
  const int qg   = (lane & 3) ^ ((lane >> 3) & 3); // staging global chunk
  const int sA   = quad ^ ((l16 >> 1) & 3);        // fragment LDS slot

  const int hb    = 16 * (wave & 1);
  const int mwave = 64 * (wave >> 1);
  const int j  = j0 + hb + l16;
  const int uA = 4 * (wave >> 1);     // A fragment unit base (+mi)
  const int uB = wave & 1;            // B fragment unit base (2p + uB)
  const int aoff = l16 * 32 + sA * 8; // fragment offset within unit (halfs)

  float bv[4];
  for (int p = 0; p < 4; ++p) bv[p] = bias[p * Hd + j];

  f32x4 acc[4][4];
  for (int mi = 0; mi < 4; ++mi)
    for (int p = 0; p < 4; ++p)
      acc[mi][p] = f32x4{bv[p], bv[p], bv[p], bv[p]};

  // stage NC 32-k subtiles of A and B, then 16*NC MFMA
  auto round = [&](auto ncI, const _Float16* __restrict__ Ab, int strA,
                   const _Float16* __restrict__ Bb, int strB, int k0) {
    constexpr int NC = decltype(ncI)::value;
    __syncthreads();  // previous round's ds_reads done before overwrite
#pragma unroll
    for (int ii = 0; ii < NC * 2; ++ii) {
      int i = ii * 4 + wave;        // 0 .. NC*8-1
      int st = i >> 3, ci = i & 7;
      gload_lds16(Ab + (size_t)(m0 + ci * 16 + srow) * strA + k0 + st * 32 + qg * 8,
                  &As[st * 4096 + ci * 512]);
    }
#pragma unroll
    for (int ii = 0; ii < NC * 2; ++ii) {
      int i = ii * 4 + wave;
      int st = i >> 3, ci = i & 7;
      int ln = ci * 16 + srow;
      int gn = (ln >> 5) * Hd + j0 + (ln & 31);   // gate-major B rows
      gload_lds16(Bb + (size_t)gn * strB + k0 + st * 32 + qg * 8,
                  &Bs[st * 4096 + ci * 512]);
    }
    __syncthreads();  // drains vmcnt(0): tiles landed
#pragma unroll
    for (int st = 0; st < NC; ++st) {
      half8 a[4], bq[4];
      for (int mi = 0; mi < 4; ++mi)
        a[mi] = *(const half8*)&As[st * 4096 + (uA + mi) * 512 + aoff];
      for (int p = 0; p < 4; ++p)
        bq[p] = *(const half8*)&Bs[st * 4096 + (2 * p + uB) * 512 + aoff];
      for (int mi = 0; mi < 4; ++mi)
        for (int p = 0; p < 4; ++p)
          acc[mi][p] = __builtin_amdgcn_mfma_f32_16x16x32_f16(a[mi], bq[p],
                                                              acc[mi][p],
                                                              0, 0, 0);
    }
  };

  // x_t @ W : K = 96 = 3 subtiles, one barrier pair
  round(IC<3>{}, xp_t, KX, Wpt, KX, 0);

  // h_{t-1} @ U : 16 rounds of BK=64 (skipped at t=0, h_0 = 0)
  if (!skip_h) {
    for (int r = 0; r < 16; ++r)
      round(IC<2>{}, h_in, Hd, Upt, Hd, r * 64);
  }

  // epilogue: lane holds i,f,g,o for hidden unit j, rows quad*4+r (m89 layout)
  for (int mi = 0; mi < 4; ++mi) {
    for (int r = 0; r < 4; ++r) {
      int row = m0 + mwave + mi * 16 + quad * 4 + r;
      size_t idx = (size_t)row * Hd + j;
      float iv = sigmoidf_fast(acc[mi][0][r]);
      float fv = sigmoidf_fast(acc[mi][1][r]);
      float gv = fmaxf(acc[mi][2][r], 0.0f);   // relu candidate
      float ov = sigmoidf_fast(acc[mi][3][r]);
      float cprev = skip_h ? 0.0f : cst[idx];  // c_0 = 0 folded in
      float cv = fv * cprev + iv * gv;
      cst[idx] = cv;
      float hv = ov * fmaxf(cv, 0.0f);         // relu on cell output
      h_out[idx] = (_Float16)hv;
    }
  }
}

// ---------------------------------------------------------------------------
// y[b][o] = bd[o] + sum_k h[b][k] * Wd[k][o]
// ---------------------------------------------------------------------------
__global__ __launch_bounds__(256) void final_dense(const _Float16* __restrict__ h,
                                                   const float* __restrict__ Wd,
                                                   const float* __restrict__ bd,
                                                   float* __restrict__ y) {
  __shared__ float hs[Hd];
  __shared__ float red[8][32];
  int bi = blockIdx.x;
  for (int k = threadIdx.x; k < Hd; k += 256)
    hs[k] = (float)h[(size_t)bi * Hd + k];
  __syncthreads();
  int o  = threadIdx.x & 31;
  int ch = threadIdx.x >> 5;
  float p = 0.0f;
  if (o < NOUT) {
    int k0 = ch * (Hd / 8);
    for (int k = k0; k < k0 + (Hd / 8); ++k)
      p += hs[k] * Wd[(size_t)k * NOUT + o];
  }
  red[ch][o] = p;
  __syncthreads();
  if (threadIdx.x < NOUT) {
    float s = bd[threadIdx.x];
    for (int c2 = 0; c2 < 8; ++c2) s += red[c2][threadIdx.x];
    y[(size_t)bi * NOUT + threadIdx.x] = s;
  }
}

// ---------------------------------------------------------------------------

extern "C" void kernel_launch(void* const* d_in, const int* in_sizes, int n_in,
                              void* d_out, int out_size, void* d_ws, size_t ws_size,
                              hipStream_t stream) {
  const float* x  = (const float*)d_in[0];
  const float* W  = (const float*)d_in[1];
  const float* U  = (const float*)d_in[2];
  const float* b  = (const float*)d_in[3];
  const float* Wd = (const float*)d_in[4];
  const float* bd = (const float*)d_in[5];
  float* y = (float*)d_out;

  char* ws = (char*)d_ws;
  _Float16* xp  = (_Float16*)ws; ws += (size_t)Tseq * Bsz * KX * 2;  // 23.6 MB
  _Float16* Wpt = (_Float16*)ws; ws += (size_t)G4 * KX * 2;          // 0.79 MB
  _Float16* Upt = (_Float16*)ws; ws += (size_t)G4 * Hd * 2;          // 8.4 MB
  _Float16* hb0 = (_Float16*)ws; ws += (size_t)Bsz * Hd * 2;         // 4.2 MB
  _Float16* hb1 = (_Float16*)ws; ws += (size_t)Bsz * Hd * 2;         // 4.2 MB
  float*    cst = (float*)ws;    ws += (size_t)Bsz * Hd * 4;         // 8.4 MB

  convert_x<<<(Tseq * Bsz * KX) / 256, 256, 0, stream>>>(x, xp);
  transpose_W<<<dim3(G4 / 32, KX / 32), dim3(32, 8), 0, stream>>>(W, Wpt);
  transpose_U<<<dim3(G4 / 32, Hd / 32), dim3(32, 8), 0, stream>>>(U, Upt);

  for (int t = 0; t < Tseq; ++t) {
    const _Float16* hin  = ((t - 1) & 1) ? hb1 : hb0;   // unused at t=0
    _Float16*       hout = (t & 1) ? hb1 : hb0;
    // grid: j-blocks FAST (XCD-pinned U slices), m-blocks slow
    lstm_step<<<dim3(G4 / 128, Bsz / 128), 256, 0, stream>>>(
        xp + (size_t)t * (Bsz * KX), Wpt, Upt, b,
        (t == 0) ? hb0 : hin, hout, cst, (t == 0) ? 1 : 0);
  }

  // h_{59} is in hb1 (59 & 1 == 1)
  final_dense<<<Bsz, 256, 0, stream>>>(hb1, Wd, bd, y);
}